// Round 3
// baseline (670.801 us; speedup 1.0000x reference)
//
#include <hip/hip_runtime.h>

// SNG: sn[b,l] = 8-step majority chain (reference scan unrolled):
//   v_0 = 0; v_{i+1} = maj(x[b,i], v_i, r[b,i,l+i]); sn[b,l] = v_8
// maj with x in {0,1}, xm = -x:  v = (xm & (v|r)) | (v & r)
//
// v3: 16 outputs/thread, k-interleaved ownership so every global load/store
// instruction is a contiguous coalesced 1KB wave segment, and each block
// covers 4KB-long sequential runs per r-row (DRAM run-length theory).

#define BATCH 1024
#define PBITS 8
#define LBITS 16384
#define TLEN (PBITS + LBITS)   // 16392 ints per r-row; row i, output l reads elem l+i

typedef int v4i __attribute__((ext_vector_type(4)));

#define MAJ(v, a) v = (xm & ((v) | (a))) | ((v) & (a))

__global__ __launch_bounds__(256) void sng_kernel(const int* __restrict__ num,
                                                  const int* __restrict__ r,
                                                  int* __restrict__ out) {
    const int t = threadIdx.x;                 // 0..255
    const int b = blockIdx.x >> 2;             // 4 blocks per batch row
    const int jb = (blockIdx.x & 3) << 12;     // dword base within row (0,4096,8192,12288)

    const int nb = num[b];                     // wave-uniform -> SGPR
    // per-thread base: batch row + block chunk + own 16B slot
    const int* rb = r + (size_t)b * (PBITS * TLEN) + jb + (t << 2);

    v4i v0 = {0,0,0,0}, v1 = {0,0,0,0}, v2 = {0,0,0,0}, v3 = {0,0,0,0};

#pragma unroll
    for (int i = 0; i < PBITS; ++i) {
        const int* rp = rb + i * TLEN + i;     // diagonal shift +i
        // 4 independent contiguous-1KB wave loads (k-interleaved chunks)
        const v4i a0 = __builtin_nontemporal_load(reinterpret_cast<const v4i*>(rp));
        const v4i a1 = __builtin_nontemporal_load(reinterpret_cast<const v4i*>(rp + 1024));
        const v4i a2 = __builtin_nontemporal_load(reinterpret_cast<const v4i*>(rp + 2048));
        const v4i a3 = __builtin_nontemporal_load(reinterpret_cast<const v4i*>(rp + 3072));
        const int x = (nb >> i) & 1;
        const v4i xm = {-x, -x, -x, -x};
        MAJ(v0, a0);
        MAJ(v1, a1);
        MAJ(v2, a2);
        MAJ(v3, a3);
    }

    // out int4 index: b*4096 + chunk*1024 + k*256 + t  (each store = contiguous 1KB/wave)
    v4i* o = reinterpret_cast<v4i*>(out) + ((blockIdx.x << 10) | t);
    __builtin_nontemporal_store(v0, o);
    __builtin_nontemporal_store(v1, o + 256);
    __builtin_nontemporal_store(v2, o + 512);
    __builtin_nontemporal_store(v3, o + 768);
}

extern "C" void kernel_launch(void* const* d_in, const int* in_sizes, int n_in,
                              void* d_out, int out_size, void* d_ws, size_t ws_size,
                              hipStream_t stream) {
    const int* num = (const int*)d_in[0];   // [B] int32
    const int* r   = (const int*)d_in[1];   // [B, P, P+L] int32 (0/1)
    int* out = (int*)d_out;                 // [B, L] int32 (0/1)

    const int blocks = BATCH * 4;           // 4096 blocks, 256 thr, 16 outputs/thread
    sng_kernel<<<blocks, 256, 0, stream>>>(num, r, out);
}